// Round 12
// baseline (749.828 us; speedup 1.0000x reference)
//
#include <hip/hip_runtime.h>
#include <hip/hip_bf16.h>

#define NTOK 8192
#define DM 1024
#define DFF 4096
#define NE 8
#define TPAD 72  // max 256-row tiles: 16384/256 + 8 partials

typedef __attribute__((ext_vector_type(8))) short bf16x8;
typedef __attribute__((ext_vector_type(4))) float f32x4;

__device__ __forceinline__ ushort f2bf(float f) {
  __hip_bfloat16 h = __float2bfloat16(f);
  return *reinterpret_cast<ushort*>(&h);
}

// ---- pack W [e][K][N] fp32 -> Wp[e][nT=N/128][kt=K/64][row128][c64] bf16,
// ---- swizzle baked: ushort pos u holds col c = u ^ ((row&7)<<3). NT loads.
template <int K, int N>
__global__ void pack_w(const float* __restrict__ in, ushort* __restrict__ outp) {
  __shared__ float t[64][129];
  const int e = blockIdx.z, nT = blockIdx.x, kt = blockIdx.y;
  const float* src = in + (size_t)e * K * N + (size_t)kt * 64 * N + (size_t)nT * 128;
  const int tid = threadIdx.x;
#pragma unroll
  for (int it = 0; it < 8; ++it) {
    int idx = it * 256 + tid;
    int kl = idx >> 5, n4 = idx & 31;
    f32x4 v = __builtin_nontemporal_load(
        reinterpret_cast<const f32x4*>(src + (size_t)kl * N + n4 * 4));
    t[kl][n4 * 4 + 0] = v.x; t[kl][n4 * 4 + 1] = v.y;
    t[kl][n4 * 4 + 2] = v.z; t[kl][n4 * 4 + 3] = v.w;
  }
  __syncthreads();
  const int row = tid >> 1, half = tid & 1;
  const int s = (row & 7) << 3;
  union { ushort us[32]; uint4 q[4]; } u;
#pragma unroll
  for (int k2 = 0; k2 < 32; ++k2) u.us[k2] = f2bf(t[(half * 32 + k2) ^ s][row]);
  ushort* dst = outp + ((size_t)(e * (N / 128) + nT) * (K / 64) + kt) * 8192 + row * 64 + half * 32;
  uint4* d4 = reinterpret_cast<uint4*>(dst);
  d4[0] = u.q[0]; d4[1] = u.q[1]; d4[2] = u.q[2]; d4[3] = u.q[3];
}

// ---------------- router (fused x->bf16 conversion) ----------------
__global__ void router_kernel(const float* __restrict__ x, const float* __restrict__ router,
                              int* __restrict__ cnt, int* __restrict__ list,
                              float* __restrict__ wa, ushort* __restrict__ xb) {
  __shared__ float rl[DM * NE];  // 32 KB
  int tid = threadIdx.x;
  for (int i = tid; i < DM * NE / 4; i += 256)
    reinterpret_cast<float4*>(rl)[i] = reinterpret_cast<const float4*>(router)[i];
  __syncthreads();
  int wave = tid >> 6, lane = tid & 63;
  int tok0 = blockIdx.x * 32 + wave * 8;
  for (int tI = 0; tI < 8; ++tI) {
    int tok = tok0 + tI;
    float acc[NE];
#pragma unroll
    for (int e2 = 0; e2 < NE; ++e2) acc[e2] = 0.f;
    const float4* xr = reinterpret_cast<const float4*>(x + (size_t)tok * DM);
    ushort xo[16];
#pragma unroll
    for (int c = 0; c < 4; ++c) {
      float4 v = xr[lane * 4 + c];
      int d = lane * 16 + c * 4;
      const float* vv = reinterpret_cast<const float*>(&v);
#pragma unroll
      for (int q = 0; q < 4; ++q) {
        float xv = vv[q];
        xo[c * 4 + q] = f2bf(xv);
#pragma unroll
        for (int e2 = 0; e2 < NE; ++e2) acc[e2] += xv * rl[(d + q) * NE + e2];
      }
    }
    *reinterpret_cast<uint4*>(xb + (size_t)tok * DM + lane * 16) =
        *reinterpret_cast<const uint4*>(&xo[0]);
    *reinterpret_cast<uint4*>(xb + (size_t)tok * DM + lane * 16 + 8) =
        *reinterpret_cast<const uint4*>(&xo[8]);
    for (int off = 32; off > 0; off >>= 1) {
#pragma unroll
      for (int e2 = 0; e2 < NE; ++e2) acc[e2] += __shfl_xor(acc[e2], off, 64);
    }
    if (lane == 0) {
      int i0 = 0; float v0 = acc[0];
#pragma unroll
      for (int e2 = 1; e2 < NE; ++e2) { if (acc[e2] > v0) { v0 = acc[e2]; i0 = e2; } }
      int i1 = -1; float v1 = -3.4e38f;
#pragma unroll
      for (int e2 = 0; e2 < NE; ++e2) { if (e2 != i0 && acc[e2] > v1) { v1 = acc[e2]; i1 = e2; } }
      float e1 = expf(v1 - v0);
      float w0 = 1.f / (1.f + e1);
      float w1 = e1 / (1.f + e1);
      int s0 = atomicAdd(&cnt[i0], 1);
      list[i0 * NTOK + s0] = tok * 2;
      wa[tok * 2] = w0;
      int s1 = atomicAdd(&cnt[i1], 1);
      list[i1 * NTOK + s1] = tok * 2 + 1;
      wa[tok * 2 + 1] = w1;
    }
  }
}

// ---------------- tile table: flat tile -> (expert, tTile), BM=256 ----------------
__global__ void build_tiles(const int* __restrict__ cnt, unsigned* __restrict__ table) {
  if (threadIdx.x == 0) {
    int t = 0;
    for (int e = 0; e < NE; ++e) {
      int nt = (cnt[e] + 255) >> 8;
      for (int i = 0; i < nt; ++i) table[t++] = ((unsigned)e << 16) | (unsigned)i;
    }
    for (; t < TPAD; ++t) table[t] = 0xFFFFFFFFu;
  }
}

// ---------------- helpers ----------------
__device__ __forceinline__ void gl_lds16(unsigned long long g, void* s) {
  __builtin_amdgcn_global_load_lds(
      (const __attribute__((address_space(1))) unsigned int*)g,
      (__attribute__((address_space(3))) unsigned int*)s, 16, 0, 0);
}

#define WAITV0() asm volatile("s_waitcnt vmcnt(0)" ::: "memory")

__device__ __forceinline__ void BARRIER() {
  asm volatile("" ::: "memory");
  __builtin_amdgcn_s_barrier();
  asm volatile("" ::: "memory");
}

// ---------------- 256x256 / 16-wave / double-buffered sparse expert GEMM ----------------
// BM=BN=256, BK=64; 1024 threads (16 waves, 4M x 4N), acc[4][4]/wave (~124 unified
// regs -> 4 waves/SIMD at one block/CU = same TLP as R8's 4x128^2 but HALF the
// staged bytes/FLOP: TA duty model predicts MfmaUtil ~60% ceiling vs 30% at 128^2).
// 2-phase dbuf body (R4-verified): STAGE(next) -> COMPUTE(cur) -> vmcnt(0) -> barrier.
// Operands fully packed+pre-swizzled (R9): every stage is linear 16 KB chunks except
// pass1's A-gather (source-swizzled row gather, R8-verified zero-conflict).
template <int PASS>
__launch_bounds__(1024, 4)
__global__ void moe_gemm(const ushort* __restrict__ Xb,
                         const ushort* __restrict__ Wp,
                         ushort* __restrict__ Hp,
                         const int* __restrict__ cnt,
                         const int* __restrict__ list,
                         const unsigned* __restrict__ table,
                         const float* __restrict__ wa,
                         float* __restrict__ out) {
  constexpr int NK = (PASS == 1) ? 16 : 32;  // pass2: K=4096 split 2

  const int bid = blockIdx.x;
  const int xcd = bid & 7;
  const int j = bid >> 3;
  int t, nTile, kc;
  if (PASS == 1) { t = j % TPAD; nTile = xcd * 2 + j / TPAD; kc = 0; }  // 16 nTiles
  else           { t = j; nTile = xcd >> 1; kc = xcd & 1; }             // 4 nT x 2 kc
  unsigned td = table[t];
  if (td == 0xFFFFFFFFu) return;  // uniform exit before any barrier
  const int e = td >> 16;
  const int tTile = td & 0xFFFF;
  const int n = cnt[e];

  __shared__ __attribute__((aligned(16))) char As[2][32768];
  __shared__ __attribute__((aligned(16))) char Bs[2][32768];
  __shared__ int aL[256];
  __shared__ unsigned long long pL[256];

  const int tid = threadIdx.x;
  if (tid < 256) {
    int slot = tTile * 256 + tid;
    int sl = (slot < n) ? slot : (n - 1);
    int a = list[e * NTOK + sl];
    if constexpr (PASS == 2) aL[tid] = (slot < n) ? a : -1;
    if constexpr (PASS == 1)
      pL[tid] = (unsigned long long)(Xb + (size_t)(a >> 1) * DM);
  }
  __syncthreads();

  // staging geometry: 1024 threads x 16B = 16 KB/issue; 2 issues A + 2 issues B.
  const int sr = tid >> 3;        // 0..127 (row within 128-row issue group)
  const int sc = (tid & 7) * 16;  // byte col
  const unsigned dOff = (unsigned)(sr * 128 + sc);
  unsigned long long sA0[2];
  if constexpr (PASS == 1) {
#pragma unroll
    for (int jj = 0; jj < 2; ++jj) {
      int row = jj * 128 + sr;
      sA0[jj] = pL[row] + (unsigned)(sc ^ ((row & 7) << 4));  // source-swizzled gather
    }
  } else {
    const char* Asrc = (const char*)Hp + ((size_t)t * 64 + kc * 32) * 32768;
#pragma unroll
    for (int jj = 0; jj < 2; ++jj)
      sA0[jj] = (unsigned long long)(Asrc + jj * 16384 + dOff);
  }
  unsigned long long sB0[2];
#pragma unroll
  for (int p = 0; p < 2; ++p) {
    size_t chunk = (PASS == 1) ? ((size_t)(e * 32 + nTile * 2 + p) * 16)
                               : ((size_t)(e * 8 + nTile * 2 + p) * 64 + kc * 32);
    sB0[p] = (unsigned long long)((const char*)Wp + chunk * 16384 + dOff);
  }

  const int wv = tid >> 6, lane = tid & 63;
  const int wm = wv >> 2, wn = wv & 3;  // 4M x 4N waves, 64x64 each

  f32x4 acc[4][4];
#pragma unroll
  for (int m = 0; m < 4; ++m)
#pragma unroll
    for (int nn = 0; nn < 4; ++nn) acc[m][nn] = (f32x4){0.f, 0.f, 0.f, 0.f};

  auto STAGE = [&](int b, int kt) {
    if constexpr (PASS == 1) {
#pragma unroll
      for (int jj = 0; jj < 2; ++jj)
        gl_lds16(sA0[jj] + (unsigned)kt * 128, As[b] + jj * 16384 + dOff);
    } else {
#pragma unroll
      for (int jj = 0; jj < 2; ++jj)
        gl_lds16(sA0[jj] + (unsigned)kt * 32768, As[b] + jj * 16384 + dOff);
    }
#pragma unroll
    for (int p = 0; p < 2; ++p)
      gl_lds16(sB0[p] + (unsigned)kt * 16384, Bs[b] + p * 16384 + dOff);
  };

  auto COMPUTE = [&](int b) {
#pragma unroll
    for (int kk = 0; kk < 2; ++kk) {
      const int kb = kk * 64 + (lane >> 4) * 16;
      bf16x8 af[4], bq[4];
#pragma unroll
      for (int m = 0; m < 4; ++m) {
        int row = wm * 64 + m * 16 + (lane & 15);
        af[m] = *reinterpret_cast<const bf16x8*>(As[b] + row * 128 + (kb ^ ((row & 7) << 4)));
      }
#pragma unroll
      for (int nn = 0; nn < 4; ++nn) {
        int row = wn * 64 + nn * 16 + (lane & 15);
        bq[nn] = *reinterpret_cast<const bf16x8*>(Bs[b] + row * 128 + (kb ^ ((row & 7) << 4)));
      }
      __builtin_amdgcn_s_setprio(1);
#pragma unroll
      for (int m = 0; m < 4; ++m)
#pragma unroll
        for (int nn = 0; nn < 4; ++nn)
          acc[m][nn] = __builtin_amdgcn_mfma_f32_16x16x32_bf16(af[m], bq[nn], acc[m][nn], 0, 0, 0);
      __builtin_amdgcn_s_setprio(0);
    }
  };

  // prologue: fill buf0, drain, barrier
  STAGE(0, 0);
  WAITV0();
  BARRIER();
  int b = 0;
  for (int kt = 0; kt < NK; ++kt) {
    if (kt + 1 < NK) STAGE(b ^ 1, kt + 1);  // issue next while computing current
    COMPUTE(b);
    WAITV0();   // next-stage loads had the whole compute block to land
    BARRIER();  // WAR + next-buf visibility
    b ^= 1;
  }

  // epilogue — C/D layout: col = lane&15, row = (lane>>4)*4 + j
#pragma unroll
  for (int m = 0; m < 4; ++m) {
#pragma unroll
    for (int jr = 0; jr < 4; ++jr) {
      int lr = wm * 64 + m * 16 + (lane >> 4) * 4 + jr;  // 0..255
      if constexpr (PASS == 1) {
        // write all rows (padding rows = dup of last real row; pass2 discards)
#pragma unroll
        for (int nn = 0; nn < 4; ++nn) {
          int cg = nTile * 256 + wn * 64 + nn * 16 + (lane & 15);
          float v = acc[m][nn][jr];
          size_t us = ((size_t)t * 64 + (cg >> 6)) * 16384 + (size_t)lr * 64 +
                      ((cg & 63) ^ ((lr & 7) << 3));
          Hp[us] = f2bf(v / (1.f + expf(-v)));  // swish, packed-swizzled 256-row chunks
        }
      } else {
        int a = aL[lr];
        if (a < 0) continue;
        float w = wa[a];
        int tok = a >> 1;
        float* orow = out + (size_t)tok * DM + nTile * 256 + wn * 64 + (lane & 15);
#pragma unroll
        for (int nn = 0; nn < 4; ++nn)
          atomicAdd(&orow[nn * 16], w * acc[m][nn][jr]);  // 2 experts x 2 kc = 4 adds
      }
    }
  }
}

extern "C" void kernel_launch(void* const* d_in, const int* in_sizes, int n_in,
                              void* d_out, int out_size, void* d_ws, size_t ws_size,
                              hipStream_t stream) {
  const float* x = (const float*)d_in[0];
  const float* router = (const float*)d_in[1];
  const float* W1 = (const float*)d_in[2];
  const float* W2 = (const float*)d_in[3];
  float* out = (float*)d_out;
  char* ws = (char*)d_ws;

  // region0 [0, 80 MB): Xb (16) + Wp1 (64) during pass1; Wp2 (64) aliases it after.
  ushort* Xb  = (ushort*)(ws + 0);
  ushort* Wp1 = (ushort*)(ws + (size_t)16 * 1024 * 1024);
  ushort* Wp2 = (ushort*)(ws + 0);  // alias, used only after pass1
  size_t off = (size_t)80 * 1024 * 1024;
  ushort* Hp = (ushort*)(ws + off); off += (size_t)TPAD * 64 * 32768;  // 151 MB packed H
  int* cnt  = (int*)(ws + off); off += 256;
  int* list = (int*)(ws + off); off += (size_t)NE * NTOK * 4;
  float* wa = (float*)(ws + off); off += (size_t)NTOK * 2 * 4;
  unsigned* table = (unsigned*)(ws + off); off += TPAD * 4;

  hipMemsetAsync(out, 0, (size_t)NTOK * DM * sizeof(float), stream);
  hipMemsetAsync(cnt, 0, NE * sizeof(int), stream);

  pack_w<DM, DFF><<<dim3(DFF / 128, DM / 64, NE), 256, 0, stream>>>(W1, Wp1);
  router_kernel<<<NTOK / 32, 256, 0, stream>>>(x, router, cnt, list, wa, Xb);
  build_tiles<<<1, 64, 0, stream>>>(cnt, table);

  // pass1: 16 nTiles, tile-fastest within XCD band; grid 8 x 2 x 72
  moe_gemm<1><<<8 * 2 * TPAD, 1024, 0, stream>>>(Xb, Wp1, Hp, cnt, list, table, wa, out);

  pack_w<DFF, DM><<<dim3(DM / 128, DFF / 64, NE), 256, 0, stream>>>(W2, Wp2);

  // pass2: 4 nTiles x 2 kc mapped to the 8 XCDs; grid 8 x 72
  moe_gemm<2><<<8 * TPAD, 1024, 0, stream>>>(Xb, Wp2, Hp, cnt, list, table, wa, out);
}